// Round 4
// baseline (860.944 us; speedup 1.0000x reference)
//
#include <hip/hip_runtime.h>
#include <hip/hip_bf16.h>
#include <hip/hip_fp16.h>

// Problem constants (fixed by the reference)
#define N_GENES_MAX 5000
#define N_ELEM_MAX  4000000
#define PARAMS_PER_GENE 445
#define PADB 32768   // per-bucket slack over N/8 (~50 sigma of multinomial dev)

// R13: 8-bucket semi-sort by gene octant + fused 3-stage eval.
// Cost-model lessons baked in:
//  - R9/R11: scattered probes cost 1 L2 lane-req when L2-RESIDENT, a 64B
//    line fetch when not (R11: 495MB FETCH). 16B bin records halve request
//    count but only pay off if per-XCD working set <= 4MB.
//  - R12: random 8B scatters to an HBM-sized region cost a full 64B line
//    writeback each (227MB for 32MB ideal). Therefore: ALL writes coalesced;
//    permutation realized as gather (random reads, L3-absorbed).
// Bucket k's blocks pinned to XCD k via blockIdx%8 -> per-XCD tables 2.2MB.
//
// Tables: R11-proven 16B per-bin record {l0 f32, w f32, lc f32,
// (rh f16<<16)|lh f16}, concatenated per gene: 127+63+31 = 221 bins.
__device__ uint4 g_tab[(size_t)N_GENES_MAX * 221];
// Partitioned records {x f32 bits, gene_local u32} in 8 fixed regions of
// stride S; g_res same indexing {x_out f32, lad f32}; g_rank maps orig->pos.
__device__ uint2 g_part[(size_t)(N_ELEM_MAX / 8 + PADB) * 8];
__device__ uint2 g_res [(size_t)(N_ELEM_MAX / 8 + PADB) * 8];
__device__ unsigned g_rank[N_ELEM_MAX];
__device__ unsigned g_cursor[8];

static __device__ __forceinline__ unsigned f2h(float f) {
    union { __half h; unsigned short u; } c;
    c.h = __float2half_rn(f);
    return (unsigned)c.u;
}
static __device__ __forceinline__ float h2f(unsigned u) {
    union { unsigned short u; __half h; } c;
    c.u = (unsigned short)u;
    return __half2float(c.h);
}

// ---- wave-level primitives (64 lanes) ----
static __device__ __forceinline__ float wscan_incl(float v) {
    const int lane = threadIdx.x & 63;
    #pragma unroll
    for (int off = 1; off < 64; off <<= 1) {
        float u = __shfl_up(v, off, 64);
        if (lane >= off) v += u;
    }
    return v;
}
static __device__ __forceinline__ float wmax64(float v) {
    #pragma unroll
    for (int off = 32; off > 0; off >>= 1) v = fmaxf(v, __shfl_xor(v, off, 64));
    return v;
}
static __device__ __forceinline__ float wsum64(float v) {
    #pragma unroll
    for (int off = 32; off > 0; off >>= 1) v += __shfl_xor(v, off, 64);
    return v;
}

// ---------------------------------------------------------------------------
// Kernel 1: build per-(gene,stage) bin records into concatenated g_tab.
// grid=(G,3), block=128. (R8-verified scans; R11-verified record format.)
// Also initializes the 8 partition cursors to their region bases.
// ---------------------------------------------------------------------------
__global__ void build_knots(const float* __restrict__ params, int S) {
    const int g = blockIdx.x;
    const int t = blockIdx.y;
    const int ns[3]   = {128, 64, 32};
    const int poff[3] = {0, 255, 382};
    const int boff[3] = {0, 127, 190};

    const int tid  = threadIdx.x;
    if (g == 0 && t == 0 && tid < 8) g_cursor[tid] = (unsigned)(tid * S);

    const int n = ns[t];
    const int m = n - 1;
    const float* ph = params + (size_t)g * PARAMS_PER_GENE + poff[t];
    const float* pw = ph + n;

    __shared__ float s2[2];
    __shared__ float s_scan[128];
    __shared__ float s_h[129];
    __shared__ float s_loc[129];
    __shared__ float s_cdf[128];

    const int lane = tid & 63;
    const int wv   = tid >> 6;

    const float uw = (tid < m) ? pw[tid] : -1e30f;
    float vmax = wmax64(uw);
    if (lane == 0) s2[wv] = vmax;
    __syncthreads();
    const float mx = fmaxf(s2[0], s2[1]);
    __syncthreads();

    const float e = (tid < m) ? __expf(uw - mx) : 0.0f;

    float sc = wscan_incl(e);
    if (lane == 63) s2[wv] = sc;
    __syncthreads();
    if (wv == 1) sc += s2[0];
    s_scan[tid] = sc;
    __syncthreads();

    const float S_ = s_scan[m - 1];
    const float invS = 1.0f / S_;
    if (tid == 0) s_loc[0] = 0.0f;
    if (tid < m) s_loc[tid + 1] = (tid == m - 1) ? 1.0f : s_scan[tid] * invS;
    const float w_i = e * invS;

    const float eh = (tid < n) ? __expf(ph[tid]) : 0.0f;
    s_h[tid] = eh;
    if (tid == 0) s_h[128] = 0.0f;
    __syncthreads();

    const float term = (tid < m) ? 0.5f * (s_h[tid] + s_h[tid + 1]) * w_i : 0.0f;
    float ts = wsum64(term);
    if (lane == 0) s2[wv] = ts;
    __syncthreads();
    const float area = s2[0] + s2[1];
    __syncthreads();

    const float ia = 1.0f / area;

    float c = wscan_incl(term * ia);
    if (lane == 63) s2[wv] = c;
    __syncthreads();
    if (wv == 1) c += s2[0];
    s_scan[tid] = c;
    __syncthreads();

    if (tid == 0) s_cdf[0] = 0.0f;
    if (tid < m) s_cdf[tid + 1] = (tid == m - 1) ? 1.0f : s_scan[tid];
    __syncthreads();

    if (tid < m) {
        const float l0 = s_loc[tid];
        const float w  = s_loc[tid + 1] - l0;
        uint4 r;
        r.x = __float_as_uint(l0);
        r.y = __float_as_uint(w);
        r.z = __float_as_uint(s_cdf[tid]);
        r.w = (f2h(s_h[tid + 1] * ia) << 16) | f2h(s_h[tid] * ia);
        g_tab[(size_t)g * 221 + boff[t] + tid] = r;
    }
}

// ---------------------------------------------------------------------------
// Kernel 2: 8-way partition by gene octant. Wave-level ballot ranking;
// one atomicAdd per wave per bucket; all global writes coalesced-ish
// (~64-elem runs per bucket per wave). block=256, 8 elems/thread.
// ---------------------------------------------------------------------------
__global__ void partition_kernel(const float* __restrict__ x_in,
                                 const int* __restrict__ gix,
                                 int N, int gpb) {
    const int tid  = threadIdx.x;
    const int lane = tid & 63;
    const unsigned long long ltm = (1ull << lane) - 1ull;
    const int base = blockIdx.x * 2048;

    float xs[8]; int bk[8]; unsigned gl[8]; int rk[8];
    unsigned c0 = 0, c1 = 0, c2 = 0, c3 = 0, c4 = 0, c5 = 0, c6 = 0, c7 = 0;

    #pragma unroll
    for (int r = 0; r < 8; ++r) {
        const int idx = base + r * 256 + tid;
        int b = -1; float xv = 0.f; unsigned g = 0;
        if (idx < N) {
            xv = x_in[idx];
            const int gg = gix[idx];
            b = gg / gpb;
            g = (unsigned)(gg - b * gpb);
        }
        xs[r] = xv; gl[r] = g; bk[r] = b;
        int mr = 0;
        #define PB(bb, cv) { \
            const unsigned long long m_ = __ballot(b == (bb)); \
            if (b == (bb)) mr = (int)(cv) + (int)__popcll(m_ & ltm); \
            cv += (unsigned)__popcll(m_); }
        PB(0, c0) PB(1, c1) PB(2, c2) PB(3, c3)
        PB(4, c4) PB(5, c5) PB(6, c6) PB(7, c7)
        #undef PB
        rk[r] = mr;
    }

    unsigned b0 = 0, b1 = 0, b2 = 0, b3 = 0, b4 = 0, b5 = 0, b6 = 0, b7 = 0;
    if (lane == 0) {
        b0 = atomicAdd(&g_cursor[0], c0);
        b1 = atomicAdd(&g_cursor[1], c1);
        b2 = atomicAdd(&g_cursor[2], c2);
        b3 = atomicAdd(&g_cursor[3], c3);
        b4 = atomicAdd(&g_cursor[4], c4);
        b5 = atomicAdd(&g_cursor[5], c5);
        b6 = atomicAdd(&g_cursor[6], c6);
        b7 = atomicAdd(&g_cursor[7], c7);
    }
    b0 = (unsigned)__shfl((int)b0, 0, 64);
    b1 = (unsigned)__shfl((int)b1, 0, 64);
    b2 = (unsigned)__shfl((int)b2, 0, 64);
    b3 = (unsigned)__shfl((int)b3, 0, 64);
    b4 = (unsigned)__shfl((int)b4, 0, 64);
    b5 = (unsigned)__shfl((int)b5, 0, 64);
    b6 = (unsigned)__shfl((int)b6, 0, 64);
    b7 = (unsigned)__shfl((int)b7, 0, 64);

    #pragma unroll
    for (int r = 0; r < 8; ++r) {
        const int idx = base + r * 256 + tid;
        if (idx < N) {
            const int b = bk[r];
            const unsigned basep =
                b == 0 ? b0 : b == 1 ? b1 : b == 2 ? b2 : b == 3 ? b3 :
                b == 4 ? b4 : b == 5 ? b5 : b == 6 ? b6 : b7;
            const unsigned pos = basep + (unsigned)rk[r];
            uint2 rec;
            rec.x = __float_as_uint(xs[r]);
            rec.y = gl[r];
            g_part[pos] = rec;
            g_rank[idx] = pos;
        }
    }
}

// ---------------------------------------------------------------------------
// Stage evaluation: ONE aligned 16B load per probe (R11-verified logic).
// ---------------------------------------------------------------------------
template <int K>
static __device__ __forceinline__ void stageb(const uint4* __restrict__ bins,
                                              float& x, float& lad) {
    int b = (int)(x * (float)(K - 1));
    b = (b < 0) ? 0 : ((b > K - 2) ? K - 2 : b);
    uint4 r = bins[b];
    float l0 = __uint_as_float(r.x);
    float w  = __uint_as_float(r.y);
    while (b > 0 && l0 > x) {
        --b;
        r = bins[b];
        l0 = __uint_as_float(r.x);
        w  = __uint_as_float(r.y);
    }
    while (b < K - 2 && l0 + w <= x) {
        ++b;
        r = bins[b];
        l0 = __uint_as_float(r.x);
        w  = __uint_as_float(r.y);
    }
    const float lh = h2f(r.w & 0xffffu);
    const float rh = h2f(r.w >> 16);
    const float lc = __uint_as_float(r.z);
    const float alpha = (x - l0) / w;
    float o = (0.5f * (rh - lh) * w) * alpha * alpha + (lh * w) * alpha + lc;
    o = fminf(fmaxf(o, 0.0f), 1.0f);
    lad += __logf(alpha * (rh - lh) + lh);
    x = o;
}

// ---------------------------------------------------------------------------
// Kernel 3: fused 3-stage eval. Block o serves bucket o&7 (= XCD o%8 by
// dispatch round-robin), so each XCD's L2 holds only its 2.2MB table slice.
// Reads/writes coalesced; lad f32 end-to-end.
// ---------------------------------------------------------------------------
__global__ void eval_kernel(int S, int gpb) {
    const int o = blockIdx.x;
    const int b = o & 7;
    const int chunk = o >> 3;
    const unsigned end = g_cursor[b];  // post-partition: region base + count
    unsigned idx = (unsigned)b * (unsigned)S + (unsigned)chunk * 1024u + threadIdx.x;
    #pragma unroll
    for (int e = 0; e < 4; ++e, idx += 256u) {
        if (idx < end) {
            const uint2 rec = g_part[idx];
            float x = __uint_as_float(rec.x);
            float lad = 0.f;
            const uint4* t = g_tab + (size_t)(b * gpb + (int)rec.y) * 221;
            stageb<128>(t, x, lad);
            stageb<64>(t + 127, x, lad);
            stageb<32>(t + 190, x, lad);
            uint2 res;
            res.x = __float_as_uint(x);
            res.y = __float_as_uint(lad);
            g_res[idx] = res;
        }
    }
}

typedef float fvec4 __attribute__((ext_vector_type(4)));
typedef unsigned uvec4 __attribute__((ext_vector_type(4)));

// ---------------------------------------------------------------------------
// Kernel 4: unpermute as GATHER: out[j] = g_res[rank[j]]. Random 8B reads
// (L3-absorbed), coalesced writes — avoids R12's write-allocate blowup.
// ---------------------------------------------------------------------------
__global__ void unpermute_kernel(float* __restrict__ out, int N) {
    const int j = (blockIdx.x * 256 + threadIdx.x) * 4;
    if (j + 3 < N) {
        const uvec4 rv = *(const uvec4*)(g_rank + j);
        const uint2 r0 = g_res[rv.x];
        const uint2 r1 = g_res[rv.y];
        const uint2 r2 = g_res[rv.z];
        const uint2 r3 = g_res[rv.w];
        fvec4 xo, lo;
        xo.x = __uint_as_float(r0.x); xo.y = __uint_as_float(r1.x);
        xo.z = __uint_as_float(r2.x); xo.w = __uint_as_float(r3.x);
        lo.x = __uint_as_float(r0.y); lo.y = __uint_as_float(r1.y);
        lo.z = __uint_as_float(r2.y); lo.w = __uint_as_float(r3.y);
        __builtin_nontemporal_store(xo, (fvec4*)(out + j));
        __builtin_nontemporal_store(lo, (fvec4*)(out + N + j));
    } else {
        for (int k = j; k < N; ++k) {
            const uint2 rr = g_res[g_rank[k]];
            out[k] = __uint_as_float(rr.x);
            out[N + k] = __uint_as_float(rr.y);
        }
    }
}

// ---------------------------------------------------------------------------
extern "C" void kernel_launch(void* const* d_in, const int* in_sizes, int n_in,
                              void* d_out, int out_size, void* d_ws, size_t ws_size,
                              hipStream_t stream) {
    const float* x      = (const float*)d_in[0];
    const int*   gix    = (const int*)d_in[1];
    const float* params = (const float*)d_in[2];
    float* out = (float*)d_out;

    const int N = in_sizes[0];
    const int G = in_sizes[2] / PARAMS_PER_GENE;
    const int gpb = (G + 7) / 8;       // genes per bucket
    const int S = N / 8 + PADB;        // per-bucket region stride

    // 1) tables + cursor init
    build_knots<<<dim3(G, 3), 128, 0, stream>>>(params, S);
    // 2) 8-way partition
    partition_kernel<<<(N + 2047) / 2048, 256, 0, stream>>>(x, gix, N, gpb);
    // 3) fused eval, bucket->XCD pinned
    const int nbe = (S + 1023) / 1024;
    eval_kernel<<<8 * nbe, 256, 0, stream>>>(S, gpb);
    // 4) gather back to original order
    unpermute_kernel<<<(N + 1023) / 1024, 256, 0, stream>>>(out, N);
}

// Round 5
// 307.496 us; speedup vs baseline: 2.7999x; 2.7999x over previous
//
#include <hip/hip_runtime.h>
#include <hip/hip_bf16.h>
#include <hip/hip_fp16.h>

// Problem constants (fixed by the reference)
#define N_GENES_MAX 5000
#define N_ELEM_MAX  4000000
#define PARAMS_PER_GENE 445
#define PADB 32768   // per-bucket slack over N/8 (~50 sigma of multinomial dev)

// R14: 8-bucket semi-sort by gene octant + fused 3-stage eval.
// Cost-model lessons:
//  - R9/R11: scattered probes cost 1 L2 lane-req when table L2-RESIDENT,
//    a 64B line fetch when not. 16B bin records halve request count but
//    only pay off if per-XCD working set <= 4MB (bucket slice = 2.2MB).
//  - R12: random small scatters to an HBM-sized region cost a 64B line
//    writeback each. ALL writes coalesced; unpermute = gather.
//  - R13: 500K same-cacheline atomics serialize (~620us). Fix: one atomic
//    per bucket per BLOCK (LDS hierarchy) + cursors padded to 128B lines.
//
// Tables: R11-proven 16B per-bin record {l0 f32, w f32, lc f32,
// (rh f16<<16)|lh f16}, concatenated per gene: 127+63+31 = 221 bins.
__device__ uint4 g_tab[(size_t)N_GENES_MAX * 221];
// Partitioned records {x f32 bits, gene_local u32} in 8 fixed regions of
// stride S; g_res same indexing {x_out f32, lad f32}; g_rank maps orig->pos.
__device__ uint2 g_part[(size_t)(N_ELEM_MAX / 8 + PADB) * 8];
__device__ uint2 g_res [(size_t)(N_ELEM_MAX / 8 + PADB) * 8];
__device__ unsigned g_rank[N_ELEM_MAX];
__device__ unsigned g_cursor[8 * 32];   // one live counter per 128B line

static __device__ __forceinline__ unsigned f2h(float f) {
    union { __half h; unsigned short u; } c;
    c.h = __float2half_rn(f);
    return (unsigned)c.u;
}
static __device__ __forceinline__ float h2f(unsigned u) {
    union { unsigned short u; __half h; } c;
    c.u = (unsigned short)u;
    return __half2float(c.h);
}

// ---- wave-level primitives (64 lanes) ----
static __device__ __forceinline__ float wscan_incl(float v) {
    const int lane = threadIdx.x & 63;
    #pragma unroll
    for (int off = 1; off < 64; off <<= 1) {
        float u = __shfl_up(v, off, 64);
        if (lane >= off) v += u;
    }
    return v;
}
static __device__ __forceinline__ float wmax64(float v) {
    #pragma unroll
    for (int off = 32; off > 0; off >>= 1) v = fmaxf(v, __shfl_xor(v, off, 64));
    return v;
}
static __device__ __forceinline__ float wsum64(float v) {
    #pragma unroll
    for (int off = 32; off > 0; off >>= 1) v += __shfl_xor(v, off, 64);
    return v;
}

// ---------------------------------------------------------------------------
// Kernel 1: build per-(gene,stage) bin records into concatenated g_tab.
// grid=(G,3), block=128. (R8-verified scans; R11-verified record format.)
// Also initializes the 8 partition cursors to their region bases.
// ---------------------------------------------------------------------------
__global__ void build_knots(const float* __restrict__ params, int S) {
    const int g = blockIdx.x;
    const int t = blockIdx.y;
    const int ns[3]   = {128, 64, 32};
    const int poff[3] = {0, 255, 382};
    const int boff[3] = {0, 127, 190};

    const int tid  = threadIdx.x;
    if (g == 0 && t == 0 && tid < 8) g_cursor[tid * 32] = (unsigned)(tid * S);

    const int n = ns[t];
    const int m = n - 1;
    const float* ph = params + (size_t)g * PARAMS_PER_GENE + poff[t];
    const float* pw = ph + n;

    __shared__ float s2[2];
    __shared__ float s_scan[128];
    __shared__ float s_h[129];
    __shared__ float s_loc[129];
    __shared__ float s_cdf[128];

    const int lane = tid & 63;
    const int wv   = tid >> 6;

    const float uw = (tid < m) ? pw[tid] : -1e30f;
    float vmax = wmax64(uw);
    if (lane == 0) s2[wv] = vmax;
    __syncthreads();
    const float mx = fmaxf(s2[0], s2[1]);
    __syncthreads();

    const float e = (tid < m) ? __expf(uw - mx) : 0.0f;

    float sc = wscan_incl(e);
    if (lane == 63) s2[wv] = sc;
    __syncthreads();
    if (wv == 1) sc += s2[0];
    s_scan[tid] = sc;
    __syncthreads();

    const float S_ = s_scan[m - 1];
    const float invS = 1.0f / S_;
    if (tid == 0) s_loc[0] = 0.0f;
    if (tid < m) s_loc[tid + 1] = (tid == m - 1) ? 1.0f : s_scan[tid] * invS;
    const float w_i = e * invS;

    const float eh = (tid < n) ? __expf(ph[tid]) : 0.0f;
    s_h[tid] = eh;
    if (tid == 0) s_h[128] = 0.0f;
    __syncthreads();

    const float term = (tid < m) ? 0.5f * (s_h[tid] + s_h[tid + 1]) * w_i : 0.0f;
    float ts = wsum64(term);
    if (lane == 0) s2[wv] = ts;
    __syncthreads();
    const float area = s2[0] + s2[1];
    __syncthreads();

    const float ia = 1.0f / area;

    float c = wscan_incl(term * ia);
    if (lane == 63) s2[wv] = c;
    __syncthreads();
    if (wv == 1) c += s2[0];
    s_scan[tid] = c;
    __syncthreads();

    if (tid == 0) s_cdf[0] = 0.0f;
    if (tid < m) s_cdf[tid + 1] = (tid == m - 1) ? 1.0f : s_scan[tid];
    __syncthreads();

    if (tid < m) {
        const float l0 = s_loc[tid];
        const float w  = s_loc[tid + 1] - l0;
        uint4 r;
        r.x = __float_as_uint(l0);
        r.y = __float_as_uint(w);
        r.z = __float_as_uint(s_cdf[tid]);
        r.w = (f2h(s_h[tid + 1] * ia) << 16) | f2h(s_h[tid] * ia);
        g_tab[(size_t)g * 221 + boff[t] + tid] = r;
    }
}

// ---------------------------------------------------------------------------
// Kernel 2: 8-way partition by gene octant. Wave ballot ranking -> LDS wave
// counts -> ONE atomicAdd per bucket per BLOCK (cursors on separate 128B
// lines) -> per-wave bases via LDS prefix. block=256, 8 elems/thread.
// ---------------------------------------------------------------------------
__global__ void partition_kernel(const float* __restrict__ x_in,
                                 const int* __restrict__ gix,
                                 int N, int gpb) {
    const int tid  = threadIdx.x;
    const int lane = tid & 63;
    const int wv   = tid >> 6;
    const unsigned long long ltm = (1ull << lane) - 1ull;
    const int base = blockIdx.x * 2048;

    __shared__ unsigned s_wcnt[4][8];
    __shared__ unsigned s_wbase[4][8];

    float xs[8]; int bk[8]; unsigned gl[8]; int rk[8];
    unsigned c0 = 0, c1 = 0, c2 = 0, c3 = 0, c4 = 0, c5 = 0, c6 = 0, c7 = 0;

    #pragma unroll
    for (int r = 0; r < 8; ++r) {
        const int idx = base + r * 256 + tid;
        int b = -1; float xv = 0.f; unsigned g = 0;
        if (idx < N) {
            xv = x_in[idx];
            const int gg = gix[idx];
            b = gg / gpb;
            g = (unsigned)(gg - b * gpb);
        }
        xs[r] = xv; gl[r] = g; bk[r] = b;
        int mr = 0;
        #define PB(bb, cv) { \
            const unsigned long long m_ = __ballot(b == (bb)); \
            if (b == (bb)) mr = (int)(cv) + (int)__popcll(m_ & ltm); \
            cv += (unsigned)__popcll(m_); }
        PB(0, c0) PB(1, c1) PB(2, c2) PB(3, c3)
        PB(4, c4) PB(5, c5) PB(6, c6) PB(7, c7)
        #undef PB
        rk[r] = mr;
    }

    if (lane == 0) {
        s_wcnt[wv][0] = c0; s_wcnt[wv][1] = c1;
        s_wcnt[wv][2] = c2; s_wcnt[wv][3] = c3;
        s_wcnt[wv][4] = c4; s_wcnt[wv][5] = c5;
        s_wcnt[wv][6] = c6; s_wcnt[wv][7] = c7;
    }
    __syncthreads();

    if (tid < 8) {
        const unsigned t0 = s_wcnt[0][tid];
        const unsigned t1 = s_wcnt[1][tid];
        const unsigned t2 = s_wcnt[2][tid];
        const unsigned t3 = s_wcnt[3][tid];
        const unsigned tot = t0 + t1 + t2 + t3;
        const unsigned bb = tot ? atomicAdd(&g_cursor[tid * 32], tot) : 0u;
        s_wbase[0][tid] = bb;
        s_wbase[1][tid] = bb + t0;
        s_wbase[2][tid] = bb + t0 + t1;
        s_wbase[3][tid] = bb + t0 + t1 + t2;
    }
    __syncthreads();

    #pragma unroll
    for (int r = 0; r < 8; ++r) {
        const int idx = base + r * 256 + tid;
        if (idx < N) {
            const int b = bk[r];
            const unsigned pos = s_wbase[wv][b] + (unsigned)rk[r];
            uint2 rec;
            rec.x = __float_as_uint(xs[r]);
            rec.y = gl[r];
            g_part[pos] = rec;
            g_rank[idx] = pos;
        }
    }
}

// ---------------------------------------------------------------------------
// Stage evaluation: ONE aligned 16B load per probe (R11-verified logic).
// ---------------------------------------------------------------------------
template <int K>
static __device__ __forceinline__ void stageb(const uint4* __restrict__ bins,
                                              float& x, float& lad) {
    int b = (int)(x * (float)(K - 1));
    b = (b < 0) ? 0 : ((b > K - 2) ? K - 2 : b);
    uint4 r = bins[b];
    float l0 = __uint_as_float(r.x);
    float w  = __uint_as_float(r.y);
    while (b > 0 && l0 > x) {
        --b;
        r = bins[b];
        l0 = __uint_as_float(r.x);
        w  = __uint_as_float(r.y);
    }
    while (b < K - 2 && l0 + w <= x) {
        ++b;
        r = bins[b];
        l0 = __uint_as_float(r.x);
        w  = __uint_as_float(r.y);
    }
    const float lh = h2f(r.w & 0xffffu);
    const float rh = h2f(r.w >> 16);
    const float lc = __uint_as_float(r.z);
    const float alpha = (x - l0) / w;
    float o = (0.5f * (rh - lh) * w) * alpha * alpha + (lh * w) * alpha + lc;
    o = fminf(fmaxf(o, 0.0f), 1.0f);
    lad += __logf(alpha * (rh - lh) + lh);
    x = o;
}

// ---------------------------------------------------------------------------
// Kernel 3: fused 3-stage eval. Block o serves bucket o&7 (= XCD o%8 by
// dispatch round-robin), so each XCD's L2 holds only its 2.2MB table slice.
// Reads/writes coalesced; lad f32 end-to-end.
// ---------------------------------------------------------------------------
__global__ void eval_kernel(int S, int gpb) {
    const int o = blockIdx.x;
    const int b = o & 7;
    const int chunk = o >> 3;
    const unsigned end = g_cursor[b * 32];  // post-partition: base + count
    unsigned idx = (unsigned)b * (unsigned)S + (unsigned)chunk * 1024u + threadIdx.x;
    #pragma unroll
    for (int e = 0; e < 4; ++e, idx += 256u) {
        if (idx < end) {
            const uint2 rec = g_part[idx];
            float x = __uint_as_float(rec.x);
            float lad = 0.f;
            const uint4* t = g_tab + (size_t)(b * gpb + (int)rec.y) * 221;
            stageb<128>(t, x, lad);
            stageb<64>(t + 127, x, lad);
            stageb<32>(t + 190, x, lad);
            uint2 res;
            res.x = __float_as_uint(x);
            res.y = __float_as_uint(lad);
            g_res[idx] = res;
        }
    }
}

typedef float fvec4 __attribute__((ext_vector_type(4)));
typedef unsigned uvec4 __attribute__((ext_vector_type(4)));

// ---------------------------------------------------------------------------
// Kernel 4: unpermute as GATHER: out[j] = g_res[rank[j]]. Random 8B reads
// (L3-absorbed), coalesced writes — avoids R12's write-allocate blowup.
// ---------------------------------------------------------------------------
__global__ void unpermute_kernel(float* __restrict__ out, int N) {
    const int j = (blockIdx.x * 256 + threadIdx.x) * 4;
    if (j + 3 < N) {
        const uvec4 rv = *(const uvec4*)(g_rank + j);
        const uint2 r0 = g_res[rv.x];
        const uint2 r1 = g_res[rv.y];
        const uint2 r2 = g_res[rv.z];
        const uint2 r3 = g_res[rv.w];
        fvec4 xo, lo;
        xo.x = __uint_as_float(r0.x); xo.y = __uint_as_float(r1.x);
        xo.z = __uint_as_float(r2.x); xo.w = __uint_as_float(r3.x);
        lo.x = __uint_as_float(r0.y); lo.y = __uint_as_float(r1.y);
        lo.z = __uint_as_float(r2.y); lo.w = __uint_as_float(r3.y);
        __builtin_nontemporal_store(xo, (fvec4*)(out + j));
        __builtin_nontemporal_store(lo, (fvec4*)(out + N + j));
    } else {
        for (int k = j; k < N; ++k) {
            const uint2 rr = g_res[g_rank[k]];
            out[k] = __uint_as_float(rr.x);
            out[N + k] = __uint_as_float(rr.y);
        }
    }
}

// ---------------------------------------------------------------------------
extern "C" void kernel_launch(void* const* d_in, const int* in_sizes, int n_in,
                              void* d_out, int out_size, void* d_ws, size_t ws_size,
                              hipStream_t stream) {
    const float* x      = (const float*)d_in[0];
    const int*   gix    = (const int*)d_in[1];
    const float* params = (const float*)d_in[2];
    float* out = (float*)d_out;

    const int N = in_sizes[0];
    const int G = in_sizes[2] / PARAMS_PER_GENE;
    const int gpb = (G + 7) / 8;       // genes per bucket
    const int S = N / 8 + PADB;        // per-bucket region stride

    // 1) tables + cursor init
    build_knots<<<dim3(G, 3), 128, 0, stream>>>(params, S);
    // 2) 8-way partition (block-level atomics only)
    partition_kernel<<<(N + 2047) / 2048, 256, 0, stream>>>(x, gix, N, gpb);
    // 3) fused eval, bucket->XCD pinned
    const int nbe = (S + 1023) / 1024;
    eval_kernel<<<8 * nbe, 256, 0, stream>>>(S, gpb);
    // 4) gather back to original order
    unpermute_kernel<<<(N + 1023) / 1024, 256, 0, stream>>>(out, N);
}